// Round 3
// baseline (56.312 us; speedup 1.0000x reference)
//
#include <hip/hip_runtime.h>

// Problem constants: B=32768, D=1024, K=8, NS=10
#define D_LEN 1024
#define K_LEN 8
#define PAD   7            // K-1
#define LC    516          // ((D + 2*PAD) - K)/2 + 1
#define NS    10

typedef float floatx4 __attribute__((ext_vector_type(4)));  // native vec for nontemporal builtins

// One block (256 threads) per row.
//   Phase 1: row -> LDS via float4; keep own 4 elems in regs.
//   Phase 2: thread computes (lo,hi) for c = 2*tid, 2*tid+1.
//            Interior (tid>=2): window x[4t-8..4t+3] = 2x ds_read_b128 + own regs,
//            all tap positions compile-time -> pure FMAs. Writes interleaved
//            float2 (lo,hi) pairs with ONE ds_write_b128.
//            NOTE: recon never reads c>511, so c=512..515 is skipped entirely.
//   Sparse:  10 uniform-index adds into the pair array.
//   Phase 3: thread computes out[4*tid .. 4*tid+3]. Interior taps collapse to
//            5 consecutive (lo,hi) pairs = 3x ds_read_b128, static positions.
//            Reflection preserves parity -> 4 taps per filter per output.
__global__ __launch_bounds__(256) void wavecore_kernel(
    const float* __restrict__ x,
    const float* __restrict__ dec_lo, const float* __restrict__ dec_hi,
    const float* __restrict__ rec_lo, const float* __restrict__ rec_hi,
    const float* __restrict__ sp_c,   const int* __restrict__ sp_i,
    float* __restrict__ out)
{
    __shared__ __align__(16) float  sx[D_LEN];
    __shared__ __align__(16) float2 st[512];   // (lo,hi) pairs, c = 0..511

    const int tid = threadIdx.x;
    const size_t rowoff = (size_t)blockIdx.x * D_LEN;

    // ---- Phase 1 ----
    floatx4 xv = __builtin_nontemporal_load(((const floatx4*)(x + rowoff)) + tid);
    ((floatx4*)sx)[tid] = xv;

    float f_dlo[K_LEN], f_dhi[K_LEN], f_rlo[K_LEN], f_rhi[K_LEN];
#pragma unroll
    for (int k = 0; k < K_LEN; ++k) {
        f_dlo[k] = dec_lo[k];
        f_dhi[k] = dec_hi[k];
        f_rlo[k] = rec_lo[k];
        f_rhi[k] = rec_hi[k];
    }
    __syncthreads();

    // ---- Phase 2: lo[c] = sum_j x[refl(2c-j)] * dec_lo[j] ----
    float lo0 = 0.f, hi0 = 0.f, lo1 = 0.f, hi1 = 0.f;
    if (tid >= 2) {
        const float4 wa = ((const float4*)sx)[tid - 2];   // x[4t-8..4t-5]
        const float4 wb = ((const float4*)sx)[tid - 1];   // x[4t-4..4t-1]
        const float w[12] = { wa.x, wa.y, wa.z, wa.w,
                              wb.x, wb.y, wb.z, wb.w,
                              xv.x, xv.y, xv.z, xv.w };   // x[4t-8..4t+3]
#pragma unroll
        for (int j = 0; j < K_LEN; ++j) {
            const float v0 = w[8  - j];   // x[2c0 - j], c0 = 2*tid
            const float v1 = w[10 - j];   // x[2c1 - j], c1 = 2*tid+1
            lo0 = fmaf(v0, f_dlo[j], lo0);
            hi0 = fmaf(v0, f_dhi[j], hi0);
            lo1 = fmaf(v1, f_dlo[j], lo1);
            hi1 = fmaf(v1, f_dhi[j], hi1);
        }
    } else {
        // Boundary (c <= 3): reflect -> sx[abs(2c - j)]
#pragma unroll
        for (int q = 0; q < 2; ++q) {
            const int c = 2 * tid + q;
            float aL = 0.f, aH = 0.f;
#pragma unroll
            for (int j = 0; j < K_LEN; ++j) {
                int m = 2 * c - j;
                m = (m < 0) ? -m : m;
                const float v = sx[m];
                aL = fmaf(v, f_dlo[j], aL);
                aH = fmaf(v, f_dhi[j], aH);
            }
            if (q == 0) { lo0 = aL; hi0 = aH; }
            else        { lo1 = aL; hi1 = aH; }
        }
    }
    {
        float4 pr;
        pr.x = lo0; pr.y = hi0; pr.z = lo1; pr.w = hi1;
        ((float4*)st)[tid] = pr;             // st[2tid], st[2tid+1]
    }
    __syncthreads();

    // ---- Sparse add (indices < 1024; lo c in [512,516) unused -> skip) ----
    if (tid < NS) {
        const int s = sp_i[tid];
        const float v = sp_c[tid];
        if (s < 512)            st[s].x       += v;
        else if (s >= LC)       st[s - LC].y  += v;   // s-516 < 508 always
    }
    __syncthreads();

    // ---- Phase 3: rec + residual ----
    float res0, res1, res2, res3;
    if (tid >= 2) {
        const float4 qa = ((const float4*)st)[tid - 2]; // st[2t-4], st[2t-3]
        const float4 qb = ((const float4*)st)[tid - 1]; // st[2t-2], st[2t-1]
        const float4 qc = ((const float4*)st)[tid];     // st[2t],   st[2t+1]
        // p0..p4 = (lo,hi) at c = e-3 .. e+1,  e = 2*tid
        const float p0l = qa.z, p0h = qa.w;
        const float p1l = qb.x, p1h = qb.y;
        const float p2l = qb.z, p2h = qb.w;
        const float p3l = qc.x, p3h = qc.y;
        const float p4l = qc.z, p4h = qc.w;
        // t even: taps k=1,3,5,7 ; t odd: k=0,2,4,6  (c ascends with k)
        res0 = p0l*f_rlo[1] + p0h*f_rhi[1] + p1l*f_rlo[3] + p1h*f_rhi[3]
             + p2l*f_rlo[5] + p2h*f_rhi[5] + p3l*f_rlo[7] + p3h*f_rhi[7];
        res1 = p0l*f_rlo[0] + p0h*f_rhi[0] + p1l*f_rlo[2] + p1h*f_rhi[2]
             + p2l*f_rlo[4] + p2h*f_rhi[4] + p3l*f_rlo[6] + p3h*f_rhi[6];
        res2 = p1l*f_rlo[1] + p1h*f_rhi[1] + p2l*f_rlo[3] + p2h*f_rhi[3]
             + p3l*f_rlo[5] + p3h*f_rhi[5] + p4l*f_rlo[7] + p4h*f_rhi[7];
        res3 = p1l*f_rlo[0] + p1h*f_rhi[0] + p2l*f_rlo[2] + p2h*f_rhi[2]
             + p3l*f_rlo[4] + p3h*f_rhi[4] + p4l*f_rlo[6] + p4h*f_rhi[6];
    } else {
        // Boundary (t <= 7): dynamic reflect path
        float acc[4];
#pragma unroll
        for (int j = 0; j < 4; ++j) {
            const int t  = 4 * tid + j;
            const int k0 = ((j & 1) ^ 1);
            float a = 0.f;
#pragma unroll
            for (int i = 0; i < 4; ++i) {
                const int k = k0 + 2 * i;
                int m = t + k - PAD;
                m = (m < 0) ? -m : m;
                const float2 pv = st[m >> 1];
                a = fmaf(pv.x, f_rlo[k], a);
                a = fmaf(pv.y, f_rhi[k], a);
            }
            acc[j] = a;
        }
        res0 = acc[0]; res1 = acc[1]; res2 = acc[2]; res3 = acc[3];
    }

    floatx4 r;
    r.x = res0 + xv.x;
    r.y = res1 + xv.y;
    r.z = res2 + xv.z;
    r.w = res3 + xv.w;
    __builtin_nontemporal_store(r, ((floatx4*)(out + rowoff)) + tid);
}

extern "C" void kernel_launch(void* const* d_in, const int* in_sizes, int n_in,
                              void* d_out, int out_size, void* d_ws, size_t ws_size,
                              hipStream_t stream) {
    const float* x      = (const float*)d_in[0];
    const float* dec_lo = (const float*)d_in[1];
    const float* dec_hi = (const float*)d_in[2];
    const float* rec_lo = (const float*)d_in[3];
    const float* rec_hi = (const float*)d_in[4];
    const float* sp_c   = (const float*)d_in[5];
    const int*   sp_i   = (const int*)d_in[6];
    float* out = (float*)d_out;

    const int Brows = in_sizes[0] / D_LEN;   // 32768
    wavecore_kernel<<<Brows, 256, 0, stream>>>(x, dec_lo, dec_hi, rec_lo, rec_hi,
                                               sp_c, sp_i, out);
}